// Round 17
// baseline (46.875 us; speedup 1.0000x reference)
//
#include <hip/hip_runtime.h>
#include <hip/hip_bf16.h>
#include <math.h>

// Problem dims (fixed by reference)
constexpr int Bn = 8, Sn = 1024, Fn = 32, Dn = 128, Cc = 16;
constexpr int NSITE = Bn * Sn;

#define EPSV 1e-8f

typedef __attribute__((ext_vector_type(8))) short bf16x8;
typedef __attribute__((ext_vector_type(4))) short bf16x4;
typedef __attribute__((ext_vector_type(4))) float f32x4;

__device__ inline short f2bf(float x) {
    __hip_bfloat16 h = __float2bfloat16(x);   // RNE
    short s;
    __builtin_memcpy(&s, &h, sizeof(s));
    return s;
}

__device__ inline bf16x8 cvt8(f32x4 x0, f32x4 x1) {
    bf16x8 r;
    r[0] = f2bf(x0[0]); r[1] = f2bf(x0[1]); r[2] = f2bf(x0[2]); r[3] = f2bf(x0[3]);
    r[4] = f2bf(x1[0]); r[5] = f2bf(x1[1]); r[6] = f2bf(x1[2]); r[7] = f2bf(x1[3]);
    return r;
}

// ---- DPP 16-lane rotation all-reduce (VALU-latency, no LDS pipe) ----
template<int CTRL>
__device__ __forceinline__ float dpp_add(float v) {
    union { float f; int i; } u, r;
    u.f = v;
    r.i = __builtin_amdgcn_update_dpp(0, u.i, CTRL, 0xf, 0xf, true);
    return v + r.f;
}
__device__ __forceinline__ float rowsum16(float v) {
    v = dpp_add<0x121>(v);   // row_ror:1
    v = dpp_add<0x122>(v);   // row_ror:2
    v = dpp_add<0x124>(v);   // row_ror:4
    v = dpp_add<0x128>(v);   // row_ror:8
    return v;
}
__device__ __forceinline__ float fastrcp(float x) { return __builtin_amdgcn_rcpf(x); }

// ---------------------------------------------------------------------------
// Fused prep: blocks 0..63 pack W into bf16 MFMA B-fragment layout;
// blocks 64..79 normalize Cj and pack into the same layout.
// frag = (n>>4)*4 + (k>>5); lane = ((k>>3)&3)*16 + (n&15); j = k&7
// ---------------------------------------------------------------------------
__global__ void prep_kernel(const float* __restrict__ Cj,
                            const float* __restrict__ W,
                            short* __restrict__ CnPack,
                            short* __restrict__ Wb) {
    const int tid = threadIdx.x;
    if (blockIdx.x < 64) {
        int t = blockIdx.x * 256 + tid;   // 16384 total
        int n = t >> 7, k = t & 127;
        short v = f2bf(W[n * Dn + k]);
        int frag = (n >> 4) * 4 + (k >> 5);
        int lane = ((k >> 3) & 3) * 16 + (n & 15);
        Wb[(frag * 64 + lane) * 8 + (k & 7)] = v;
    } else {
        int c = blockIdx.x - 64;          // 16 blocks
        __shared__ float part[2];
        float v = 0.f, sq = 0.f;
        if (tid < 128) {
            v = Cj[c * Dn + tid];
            sq = v * v;
            #pragma unroll
            for (int off = 32; off > 0; off >>= 1) sq += __shfl_down(sq, off);
        }
        if (tid < 128 && (tid & 63) == 0) part[tid >> 6] = sq;
        __syncthreads();
        if (tid < 128) {
            float cn = v / fmaxf(sqrtf(part[0] + part[1]), EPSV);
            int kt = tid >> 5, ln = ((tid >> 3) & 3) * 16 + c, j = tid & 7;
            CnPack[(kt * 64 + ln) * 8 + j] = f2bf(cn);
        }
    }
}

// ---------------------------------------------------------------------------
// Site kernel: 512-thread blocks = 8 independent waves, one site each.
// Wb (32 KB) is STAGED INTO LDS once per block -> the Linear nt-loop's
// fragment loads become ds_read_b128 (~60 cy, un-thrashable) instead of
// L2 round-trips (~250 cy; the 32KB L1 can't hold Wb against 8 waves
// streaming 16KB of Hs each). One barrier after staging; Hs loads are
// issued BEFORE staging so HBM latency hides under it.
// LDS = 32KB sWb + 8 x 2.5KB Ft = 52 KB -> 3 blocks/CU = 24 waves/CU.
// __launch_bounds__(512,4) = the proven 128-VGPR cap.
// ---------------------------------------------------------------------------
__launch_bounds__(512, 4)
__global__ void site_kernel(const float* __restrict__ Hs,
                            const short* __restrict__ CnPack,
                            const short* __restrict__ Wb,
                            const float* __restrict__ bvec,
                            const float* __restrict__ imp_in,
                            float* __restrict__ f_out,
                            float* __restrict__ imp_out) {
    __shared__ __align__(16) short sWb[16384];         // 32 KB, frag-linear
    __shared__ __align__(16) short Ft[8][2][16][40];   // 20 KB ping-pong tiles

    const int tid  = threadIdx.x;
    const int lane = tid & 63;
    const int wv   = tid >> 6;
    const int c16  = lane & 15;
    const int g    = lane >> 4;
    const int site = blockIdx.x * 8 + wv;

    const float* hsrc = Hs + (size_t)site * (Fn * Dn);
    const f32x4 zro = {0.f, 0.f, 0.f, 0.f};

    // ---- issue all global loads early (16 x dwordx4 Hs + tables) ----
    f32x4 x[16];
    #pragma unroll
    for (int kt = 0; kt < 4; ++kt) {
        const f32x4* p0 = (const f32x4*)(hsrc + c16 * Dn + kt * 32 + g * 8);
        const f32x4* p1 = (const f32x4*)(hsrc + (16 + c16) * Dn + kt * 32 + g * 8);
        x[4 * kt + 0] = p0[0];
        x[4 * kt + 1] = p0[1];
        x[4 * kt + 2] = p1[0];
        x[4 * kt + 3] = p1[1];
    }
    bf16x8 bcf[4];
    #pragma unroll
    for (int kt = 0; kt < 4; ++kt)
        bcf[kt] = *(const bf16x8*)&CnPack[(kt * 64 + lane) * 8];
    const float* impp = imp_in + (size_t)site * Fn;
    f32x4 impv0 = *(const f32x4*)(impp + 4 * g);        // imp[4g+r]
    f32x4 impv1 = *(const f32x4*)(impp + 16 + 4 * g);   // imp[16+4g+r]

    // ---- cooperative Wb -> LDS staging (2048 x 16B, 4 per thread) ----
    {
        const f32x4* src = (const f32x4*)Wb;
        f32x4* dst = (f32x4*)sWb;
        #pragma unroll
        for (int i = 0; i < 4; ++i) dst[tid + i * 512] = src[tid + i * 512];
    }

    // ---- convert to bf16 A-fragments (overlaps staging latency) ----
    bf16x8 aF[2][4];
    #pragma unroll
    for (int kt = 0; kt < 4; ++kt) {
        aF[0][kt] = cvt8(x[4 * kt + 0], x[4 * kt + 1]);
        aF[1][kt] = cvt8(x[4 * kt + 2], x[4 * kt + 3]);
    }

    // ---- Gram (row norms via H.H^T diag) + cosine MFMAs (16 MFMA) ----
    f32x4 gm0 = zro, gm1 = zro, cos0 = zro, cos1 = zro;
    #pragma unroll
    for (int kt = 0; kt < 4; ++kt) {
        gm0  = __builtin_amdgcn_mfma_f32_16x16x32_bf16(aF[0][kt], aF[0][kt], gm0, 0, 0, 0);
        gm1  = __builtin_amdgcn_mfma_f32_16x16x32_bf16(aF[1][kt], aF[1][kt], gm1, 0, 0, 0);
        cos0 = __builtin_amdgcn_mfma_f32_16x16x32_bf16(aF[0][kt], bcf[kt], cos0, 0, 0, 0);
        cos1 = __builtin_amdgcn_mfma_f32_16x16x32_bf16(aF[1][kt], bcf[kt], cos1, 0, 0, 0);
    }

    // ---- logits s = 5*cos, e = exp(s); s in [-5,5] so no-max is safe;
    //      e shared by BOTH softmaxes (r13-verified) ----
    float e0[4], e1[4];
    #pragma unroll
    for (int r = 0; r < 4; ++r) {
        float q0 = __shfl(gm0[r], 20 * g + r);      // diag gather (independent)
        float q1 = __shfl(gm1[r], 20 * g + r);
        float i0 = fastrcp(fmaxf(sqrtf(q0), EPSV));
        float i1 = fastrcp(fmaxf(sqrtf(q1), EPSV));
        e0[r] = __expf(5.0f * cos0[r] * i0);        // f = 4g+r,    c = c16
        e1[r] = __expf(5.0f * cos1[r] * i1);        // f = 16+4g+r, c = c16
    }

    // ---- w: softmax over features -> B-fragment via shuffles ----
    bf16x8 wB;
    {
        float sum = 0.f;
        #pragma unroll
        for (int r = 0; r < 4; ++r) sum += e0[r] + e1[r];
        sum += __shfl_xor(sum, 16);
        sum += __shfl_xor(sum, 32);
        float inv = fastrcp(sum);
        const int srcA = c16 + 16 * ((2 * g) & 3);
        const int srcB = c16 + 16 * ((2 * g + 1) & 3);
        const bool hi = (g >= 2);
        #pragma unroll
        for (int r = 0; r < 4; ++r) {
            float a0 = __shfl(e0[r] * inv, srcA);
            float a1 = __shfl(e1[r] * inv, srcA);
            wB[r] = f2bf(hi ? a1 : a0);
            float b0 = __shfl(e0[r] * inv, srcB);
            float b1 = __shfl(e1[r] * inv, srcB);
            wB[4 + r] = f2bf(hi ? b1 : b0);
        }
    }

    // ---- w3 softmax over centers (DPP row-sums) fused with importance ----
    {
        float t = 0.f;
        #pragma unroll
        for (int h = 0; h < 2; ++h) {
            #pragma unroll
            for (int r = 0; r < 4; ++r) {
                float e = h ? e1[r] : e0[r];
                float q3 = rowsum16(e);             // sum over c (16-lane row)
                t += e * fastrcp(q3) * (h ? impv1[r] : impv0[r]);
            }
        }
        t += __shfl_xor(t, 16);
        t += __shfl_xor(t, 32);
        float ei = __expf(t);
        float si = rowsum16(ei);
        if (g == 0) imp_out[(size_t)site * Cc + c16] = ei * fastrcp(si);
    }

    __syncthreads();   // sWb ready (front-end compute hid the staging)

    // ---- fused Linear + agg: per nt, Linear MFMAs (W frags from LDS) ->
    //      tiny LDS tile -> transposed read -> agg MFMA -> float4 store ----
    float* op = f_out + (size_t)site * (Cc * Dn);
    #pragma unroll
    for (int nt = 0; nt < 8; ++nt) {
        bf16x8 bw0 = *(const bf16x8*)&sWb[((nt * 4) + 0) * 512 + lane * 8];
        bf16x8 bw1 = *(const bf16x8*)&sWb[((nt * 4) + 1) * 512 + lane * 8];
        bf16x8 bw2 = *(const bf16x8*)&sWb[((nt * 4) + 2) * 512 + lane * 8];
        bf16x8 bw3 = *(const bf16x8*)&sWb[((nt * 4) + 3) * 512 + lane * 8];
        f32x4 acc0 = zro, acc1 = zro;
        acc0 = __builtin_amdgcn_mfma_f32_16x16x32_bf16(aF[0][0], bw0, acc0, 0, 0, 0);
        acc1 = __builtin_amdgcn_mfma_f32_16x16x32_bf16(aF[1][0], bw0, acc1, 0, 0, 0);
        acc0 = __builtin_amdgcn_mfma_f32_16x16x32_bf16(aF[0][1], bw1, acc0, 0, 0, 0);
        acc1 = __builtin_amdgcn_mfma_f32_16x16x32_bf16(aF[1][1], bw1, acc1, 0, 0, 0);
        acc0 = __builtin_amdgcn_mfma_f32_16x16x32_bf16(aF[0][2], bw2, acc0, 0, 0, 0);
        acc1 = __builtin_amdgcn_mfma_f32_16x16x32_bf16(aF[1][2], bw2, acc1, 0, 0, 0);
        acc0 = __builtin_amdgcn_mfma_f32_16x16x32_bf16(aF[0][3], bw3, acc0, 0, 0, 0);
        acc1 = __builtin_amdgcn_mfma_f32_16x16x32_bf16(aF[1][3], bw3, acc1, 0, 0, 0);
        float bb = bvec[nt * 16 + c16];
        bf16x4 p0, p1;
        #pragma unroll
        for (int r = 0; r < 4; ++r) {
            p0[r] = f2bf(fmaxf(acc0[r] + bb, 0.f));
            p1[r] = f2bf(fmaxf(acc1[r] + bb, 0.f));
        }
        // lane holds F[f=4g+r | 16+4g+r][n = 16nt+c16] -> tile row c16
        *(bf16x4*)&Ft[wv][nt & 1][c16][4 * g]      = p0;   // f = 4g+r
        *(bf16x4*)&Ft[wv][nt & 1][c16][16 + 4 * g] = p1;   // f = 16+4g+r
        // transposed read: A-frag for agg = F^T[n_local=c16][f=8g+j]
        bf16x8 aFt = *(const bf16x8*)&Ft[wv][nt & 1][c16][8 * g];
        f32x4 o = __builtin_amdgcn_mfma_f32_16x16x32_bf16(aFt, wB, zro, 0, 0, 0);
        *(f32x4*)(op + c16 * Dn + nt * 16 + 4 * g) = o;
    }
}

// ---------------------------------------------------------------------------
extern "C" void kernel_launch(void* const* d_in, const int* in_sizes, int n_in,
                              void* d_out, int out_size, void* d_ws, size_t ws_size,
                              hipStream_t stream) {
    const float* Hs  = (const float*)d_in[0];
    const float* Cj  = (const float*)d_in[1];
    const float* W   = (const float*)d_in[2];
    const float* b   = (const float*)d_in[3];
    const float* imp = (const float*)d_in[4];

    float* f_out   = (float*)d_out;                          // [B,S,C,D]
    float* imp_out = f_out + (size_t)NSITE * Cc * Dn;        // [B,S,C]

    short* CnPack = (short*)d_ws;                            // 4 KB bf16 frags
    short* Wb     = CnPack + Cc * Dn;                        // 32 KB bf16 frags

    hipLaunchKernelGGL(prep_kernel, dim3(80), dim3(256), 0, stream, Cj, W, CnPack, Wb);
    hipLaunchKernelGGL(site_kernel, dim3(NSITE / 8), dim3(512), 0, stream,
                       Hs, CnPack, Wb, b, imp, f_out, imp_out);
}

// Round 18
// 44.461 us; speedup vs baseline: 1.0543x; 1.0543x over previous
//
#include <hip/hip_runtime.h>
#include <hip/hip_bf16.h>
#include <math.h>

// Problem dims (fixed by reference)
constexpr int Bn = 8, Sn = 1024, Fn = 32, Dn = 128, Cc = 16;
constexpr int NSITE = Bn * Sn;

#define EPSV 1e-8f

typedef __attribute__((ext_vector_type(8))) short bf16x8;
typedef __attribute__((ext_vector_type(4))) short bf16x4;
typedef __attribute__((ext_vector_type(4))) float f32x4;

__device__ inline short f2bf(float x) {
    __hip_bfloat16 h = __float2bfloat16(x);   // RNE
    short s;
    __builtin_memcpy(&s, &h, sizeof(s));
    return s;
}

__device__ inline bf16x8 cvt8(f32x4 x0, f32x4 x1) {
    bf16x8 r;
    r[0] = f2bf(x0[0]); r[1] = f2bf(x0[1]); r[2] = f2bf(x0[2]); r[3] = f2bf(x0[3]);
    r[4] = f2bf(x1[0]); r[5] = f2bf(x1[1]); r[6] = f2bf(x1[2]); r[7] = f2bf(x1[3]);
    return r;
}

// ---- DPP 16-lane rotation all-reduce (VALU-latency, no LDS pipe) ----
template<int CTRL>
__device__ __forceinline__ float dpp_add(float v) {
    union { float f; int i; } u, r;
    u.f = v;
    r.i = __builtin_amdgcn_update_dpp(0, u.i, CTRL, 0xf, 0xf, true);
    return v + r.f;
}
__device__ __forceinline__ float rowsum16(float v) {
    v = dpp_add<0x121>(v);   // row_ror:1
    v = dpp_add<0x122>(v);   // row_ror:2
    v = dpp_add<0x124>(v);   // row_ror:4
    v = dpp_add<0x128>(v);   // row_ror:8
    return v;
}
__device__ __forceinline__ float fastrcp(float x) { return __builtin_amdgcn_rcpf(x); }

// ---------------------------------------------------------------------------
// Fused prep: blocks 0..63 pack W into bf16 MFMA B-fragment layout;
// blocks 64..79 normalize Cj and pack into the same layout.
// frag = (n>>4)*4 + (k>>5); lane = ((k>>3)&3)*16 + (n&15); j = k&7
// ---------------------------------------------------------------------------
__global__ void prep_kernel(const float* __restrict__ Cj,
                            const float* __restrict__ W,
                            short* __restrict__ CnPack,
                            short* __restrict__ Wb) {
    const int tid = threadIdx.x;
    if (blockIdx.x < 64) {
        int t = blockIdx.x * 256 + tid;   // 16384 total
        int n = t >> 7, k = t & 127;
        short v = f2bf(W[n * Dn + k]);
        int frag = (n >> 4) * 4 + (k >> 5);
        int lane = ((k >> 3) & 3) * 16 + (n & 15);
        Wb[(frag * 64 + lane) * 8 + (k & 7)] = v;
    } else {
        int c = blockIdx.x - 64;          // 16 blocks
        __shared__ float part[2];
        float v = 0.f, sq = 0.f;
        if (tid < 128) {
            v = Cj[c * Dn + tid];
            sq = v * v;
            #pragma unroll
            for (int off = 32; off > 0; off >>= 1) sq += __shfl_down(sq, off);
        }
        if (tid < 128 && (tid & 63) == 0) part[tid >> 6] = sq;
        __syncthreads();
        if (tid < 128) {
            float cn = v / fmaxf(sqrtf(part[0] + part[1]), EPSV);
            int kt = tid >> 5, ln = ((tid >> 3) & 3) * 16 + c, j = tid & 7;
            CnPack[(kt * 64 + ln) * 8 + j] = f2bf(cn);
        }
    }
}

// ---------------------------------------------------------------------------
// Site kernel: ONE WAVE = ONE SITE (r13 structure, best measured: 46.06us),
// plus FULL-LINE STORES: agg output round-trips a tiny padded LDS tile per
// nt-pair so each store instruction writes 8 full 128B lines instead of 16
// scattered 64B half-lines (the one memory stream never restructured; L2
// partial-sector merge is the suspected wave-queue serializer).
// ---------------------------------------------------------------------------
__launch_bounds__(64, 4)
__global__ void site_kernel(const float* __restrict__ Hs,
                            const short* __restrict__ CnPack,
                            const short* __restrict__ Wb,
                            const float* __restrict__ bvec,
                            const float* __restrict__ imp_in,
                            float* __restrict__ f_out,
                            float* __restrict__ imp_out) {
    // F_tjT: [dim n][feature f] bf16, 80B rows (16B-aligned, <=2-way banks)
    __shared__ __align__(16) short F_tjT[128][40];   // 10240 B
    // sO: per-pair f32 out tile [out-row c][32 cols], +1 pad -> ~2-way banks
    __shared__ __align__(16) float sO[16][33];       // 2112 B

    const int lane = threadIdx.x;      // 0..63
    const int c16  = lane & 15;
    const int g    = lane >> 4;
    const int site = blockIdx.x;

    const float* hsrc = Hs + (size_t)site * (Fn * Dn);
    const f32x4 zro = {0.f, 0.f, 0.f, 0.f};

    // ---- issue all global loads early (16 x dwordx4 Hs) ----
    f32x4 x[16];
    #pragma unroll
    for (int kt = 0; kt < 4; ++kt) {
        const f32x4* p0 = (const f32x4*)(hsrc + c16 * Dn + kt * 32 + g * 8);
        const f32x4* p1 = (const f32x4*)(hsrc + (16 + c16) * Dn + kt * 32 + g * 8);
        x[4 * kt + 0] = p0[0];
        x[4 * kt + 1] = p0[1];
        x[4 * kt + 2] = p1[0];
        x[4 * kt + 3] = p1[1];
    }
    bf16x8 bcf[4];
    #pragma unroll
    for (int kt = 0; kt < 4; ++kt)
        bcf[kt] = *(const bf16x8*)&CnPack[(kt * 64 + lane) * 8];
    const float* impp = imp_in + (size_t)site * Fn;
    f32x4 impv0 = *(const f32x4*)(impp + 4 * g);        // imp[4g+r]
    f32x4 impv1 = *(const f32x4*)(impp + 16 + 4 * g);   // imp[16+4g+r]

    // ---- convert to bf16 A-fragments ----
    bf16x8 aF[2][4];
    #pragma unroll
    for (int kt = 0; kt < 4; ++kt) {
        aF[0][kt] = cvt8(x[4 * kt + 0], x[4 * kt + 1]);
        aF[1][kt] = cvt8(x[4 * kt + 2], x[4 * kt + 3]);
    }

    // ---- Gram (row norms via H.H^T diag) + cosine MFMAs (16 MFMA) ----
    f32x4 gm0 = zro, gm1 = zro, cos0 = zro, cos1 = zro;
    #pragma unroll
    for (int kt = 0; kt < 4; ++kt) {
        gm0  = __builtin_amdgcn_mfma_f32_16x16x32_bf16(aF[0][kt], aF[0][kt], gm0, 0, 0, 0);
        gm1  = __builtin_amdgcn_mfma_f32_16x16x32_bf16(aF[1][kt], aF[1][kt], gm1, 0, 0, 0);
        cos0 = __builtin_amdgcn_mfma_f32_16x16x32_bf16(aF[0][kt], bcf[kt], cos0, 0, 0, 0);
        cos1 = __builtin_amdgcn_mfma_f32_16x16x32_bf16(aF[1][kt], bcf[kt], cos1, 0, 0, 0);
    }

    // ---- logits s = 5*cos (softmax-shift-invariant), then e = exp(s).
    //      s in [-5,5] -> exp range-safe; e shared by BOTH softmaxes. ----
    float e0[4], e1[4];
    #pragma unroll
    for (int r = 0; r < 4; ++r) {
        float q0 = __shfl(gm0[r], 20 * g + r);      // diag gather (independent)
        float q1 = __shfl(gm1[r], 20 * g + r);
        float i0 = fastrcp(fmaxf(sqrtf(q0), EPSV));
        float i1 = fastrcp(fmaxf(sqrtf(q1), EPSV));
        e0[r] = __expf(5.0f * cos0[r] * i0);        // f = 4g+r,    c = c16
        e1[r] = __expf(5.0f * cos1[r] * i1);        // f = 16+4g+r, c = c16
    }

    // ---- w: softmax over features -> B-fragment via shuffles ----
    bf16x8 wB;
    {
        float sum = 0.f;
        #pragma unroll
        for (int r = 0; r < 4; ++r) sum += e0[r] + e1[r];
        sum += __shfl_xor(sum, 16);
        sum += __shfl_xor(sum, 32);
        float inv = fastrcp(sum);
        const int srcA = c16 + 16 * ((2 * g) & 3);
        const int srcB = c16 + 16 * ((2 * g + 1) & 3);
        const bool hi = (g >= 2);
        #pragma unroll
        for (int r = 0; r < 4; ++r) {
            float a0 = __shfl(e0[r] * inv, srcA);
            float a1 = __shfl(e1[r] * inv, srcA);
            wB[r] = f2bf(hi ? a1 : a0);
            float b0 = __shfl(e0[r] * inv, srcB);
            float b1 = __shfl(e1[r] * inv, srcB);
            wB[4 + r] = f2bf(hi ? b1 : b0);
        }
    }

    // ---- w3 softmax over centers (DPP row-sums) fused with importance ----
    {
        float t = 0.f;
        #pragma unroll
        for (int h = 0; h < 2; ++h) {
            #pragma unroll
            for (int r = 0; r < 4; ++r) {
                float e = h ? e1[r] : e0[r];
                float q3 = rowsum16(e);             // sum over c (16-lane row)
                t += e * fastrcp(q3) * (h ? impv1[r] : impv0[r]);
            }
        }
        t += __shfl_xor(t, 16);
        t += __shfl_xor(t, 32);
        // importance softmax over c: t <= 32 -> exp safe without max
        float ei = __expf(t);
        float si = rowsum16(ei);
        if (g == 0) imp_out[(size_t)site * Cc + c16] = ei * fastrcp(si);
    }

    // ---- Linear: F_tj = relu(Hs @ W^T + b), 64 MFMA, -> LDS (transposed) ----
    #pragma unroll
    for (int nt = 0; nt < 8; ++nt) {
        bf16x8 bw0 = *(const bf16x8*)&Wb[((nt * 4) + 0) * 512 + lane * 8];
        bf16x8 bw1 = *(const bf16x8*)&Wb[((nt * 4) + 1) * 512 + lane * 8];
        bf16x8 bw2 = *(const bf16x8*)&Wb[((nt * 4) + 2) * 512 + lane * 8];
        bf16x8 bw3 = *(const bf16x8*)&Wb[((nt * 4) + 3) * 512 + lane * 8];
        f32x4 acc0 = zro, acc1 = zro;
        acc0 = __builtin_amdgcn_mfma_f32_16x16x32_bf16(aF[0][0], bw0, acc0, 0, 0, 0);
        acc1 = __builtin_amdgcn_mfma_f32_16x16x32_bf16(aF[1][0], bw0, acc1, 0, 0, 0);
        acc0 = __builtin_amdgcn_mfma_f32_16x16x32_bf16(aF[0][1], bw1, acc0, 0, 0, 0);
        acc1 = __builtin_amdgcn_mfma_f32_16x16x32_bf16(aF[1][1], bw1, acc1, 0, 0, 0);
        acc0 = __builtin_amdgcn_mfma_f32_16x16x32_bf16(aF[0][2], bw2, acc0, 0, 0, 0);
        acc1 = __builtin_amdgcn_mfma_f32_16x16x32_bf16(aF[1][2], bw2, acc1, 0, 0, 0);
        acc0 = __builtin_amdgcn_mfma_f32_16x16x32_bf16(aF[0][3], bw3, acc0, 0, 0, 0);
        acc1 = __builtin_amdgcn_mfma_f32_16x16x32_bf16(aF[1][3], bw3, acc1, 0, 0, 0);
        float bb = bvec[nt * 16 + c16];
        bf16x4 p0, p1;
        #pragma unroll
        for (int r = 0; r < 4; ++r) {
            p0[r] = f2bf(fmaxf(acc0[r] + bb, 0.f));
            p1[r] = f2bf(fmaxf(acc1[r] + bb, 0.f));
        }
        *(bf16x4*)&F_tjT[nt * 16 + c16][4 * g]      = p0;   // f = 4g+r
        *(bf16x4*)&F_tjT[nt * 16 + c16][16 + 4 * g] = p1;   // f = 16+4g+r
    }

    // ---- agg + FULL-LINE stores: per nt-pair, 2 agg MFMAs -> sO tile ->
    //      2 store instructions, each writing 8 full 128B lines ----
    {
        float* op = f_out + (size_t)site * (Cc * Dn);
        #pragma unroll
        for (int p = 0; p < 4; ++p) {
            #pragma unroll
            for (int h = 0; h < 2; ++h) {
                const int nt = 2 * p + h;
                bf16x8 aFt = *(const bf16x8*)&F_tjT[nt * 16 + c16][8 * g];
                f32x4 o = __builtin_amdgcn_mfma_f32_16x16x32_bf16(aFt, wB, zro, 0, 0, 0);
                // o[r] = out[c16][nt*16 + 4g + r] -> pair-local col h*16+4g+r
                *(f32x4*)&sO[c16][h * 16 + 4 * g] = o;
            }
            // store pair p: rows 0..15, cols p*32..p*32+31 (128B/row, aligned)
            #pragma unroll
            for (int i = 0; i < 2; ++i) {
                const int row = 8 * i + (lane >> 3);
                const int cir = lane & 7;              // 16B chunk in row
                f32x4 v = *(const f32x4*)&sO[row][cir * 4];
                *(f32x4*)(op + row * Dn + p * 32 + cir * 4) = v;
            }
        }
    }
}

// ---------------------------------------------------------------------------
extern "C" void kernel_launch(void* const* d_in, const int* in_sizes, int n_in,
                              void* d_out, int out_size, void* d_ws, size_t ws_size,
                              hipStream_t stream) {
    const float* Hs  = (const float*)d_in[0];
    const float* Cj  = (const float*)d_in[1];
    const float* W   = (const float*)d_in[2];
    const float* b   = (const float*)d_in[3];
    const float* imp = (const float*)d_in[4];

    float* f_out   = (float*)d_out;                          // [B,S,C,D]
    float* imp_out = f_out + (size_t)NSITE * Cc * Dn;        // [B,S,C]

    short* CnPack = (short*)d_ws;                            // 4 KB bf16 frags
    short* Wb     = CnPack + Cc * Dn;                        // 32 KB bf16 frags

    hipLaunchKernelGGL(prep_kernel, dim3(80), dim3(256), 0, stream, Cj, W, CnPack, Wb);
    hipLaunchKernelGGL(site_kernel, dim3(NSITE), dim3(64), 0, stream,
                       Hs, CnPack, Wb, b, imp, f_out, imp_out);
}